// Round 13
// baseline (193.637 us; speedup 1.0000x reference)
//
#include <hip/hip_runtime.h>
#include <hip/hip_bf16.h>
#include <cstdint>
#include <cstddef>

#define DEVI static __device__ __forceinline__

typedef __attribute__((ext_vector_type(8))) short short8;
typedef __attribute__((ext_vector_type(4))) float f32x4;

typedef __attribute__((address_space(1))) const unsigned int as1c_uint;
typedef __attribute__((address_space(3))) unsigned int as3_uint;

constexpr int Bn = 4, Tn = 2048, Cn = 1024, Hn = 16, Dn = 64;
constexpr int Mtot = Bn * Tn;  // 8192
// Q pre-scale: (1/sqrt(D)) * log2(e) so softmax uses exp2 directly
#define QSCALE (0.125f * 1.44269504088896340736f)

DEVI unsigned short f2bf(float f) {  // RNE (projections)
  unsigned u = __float_as_uint(f);
  u += 0x7fffu + ((u >> 16) & 1u);
  return (unsigned short)(u >> 16);
}
DEVI unsigned short f2bf_t(float f) {  // truncate (P values; bias cancels in ratio)
  return (unsigned short)(__float_as_uint(f) >> 16);
}

DEVI void async16(const void* g, void* l) {
  __builtin_amdgcn_global_load_lds((as1c_uint*)g, (as3_uint*)l, 16, 0, 0);
}

// ---------- w [K][N] f32 -> frag-major wF bf16 ----------
// wF flat elem idx for (n,k):
//   (((n>>4)*32 + (k>>5))*64 + ((k>>3)&3)*16 + (n&15))*8 + (k&7)
__global__ __launch_bounds__(256) void transpose_cvt4(
    const float* __restrict__ w0, const float* __restrict__ w1,
    const float* __restrict__ w2, const float* __restrict__ w3,
    unsigned short* __restrict__ o0, unsigned short* __restrict__ o1,
    unsigned short* __restrict__ o2, unsigned short* __restrict__ o3) {
  __shared__ float tile[32][33];  // [k-local][n-local]
  const int z = blockIdx.z;
  const float* w = z == 0 ? w0 : z == 1 ? w1 : z == 2 ? w2 : w3;
  unsigned short* wT = z == 0 ? o0 : z == 1 ? o1 : z == 2 ? o2 : o3;
  int n0 = blockIdx.x * 32, k0 = blockIdx.y * 32;
  int tx = threadIdx.x, ty = threadIdx.y;  // 32 x 8
#pragma unroll
  for (int r = 0; r < 32; r += 8)
    tile[ty + r][tx] = w[(size_t)(k0 + ty + r) * Cn + n0 + tx];
  __syncthreads();
  const int t = ty * 32 + tx;        // 0..255
  const int n_l = t >> 3;            // 0..31
  const int kq = (t & 7) * 4;        // 0..28
  const int n = n0 + n_l, k = k0 + kq;
  ushort4 pk;
#pragma unroll
  for (int e = 0; e < 4; ++e) ((unsigned short*)&pk)[e] = f2bf(tile[kq + e][n_l]);
  size_t idx = (size_t)((((n >> 4) * 32 + (k >> 5)) * 64 + ((k >> 3) & 3) * 16 + (n & 15))) * 8 + (k & 7);
  *(ushort4*)&wT[idx] = pk;
}

// ---------- producer-consumer QKV projection ----------
// stage one K-half (64 rows x 512 cols) fp32 -> bf16 LDS, XOR-swizzled.
template <int NT>
DEVI void stage_half(const float* __restrict__ src, int m0, int kh,
                     unsigned short* Xbuf, int t) {
#pragma unroll
  for (int it = 0; it < 4096 / NT; ++it) {
    int g = it * NT + t;             // group of 8 floats, 4096 total
    int row = g >> 6, slot = g & 63;
    const float4* p = (const float4*)(src + (size_t)(m0 + row) * Cn + kh * 512 + slot * 8);
    float4 a = p[0], b = p[1];
    short8 sv;
    sv[0] = (short)f2bf(a.x); sv[1] = (short)f2bf(a.y);
    sv[2] = (short)f2bf(a.z); sv[3] = (short)f2bf(a.w);
    sv[4] = (short)f2bf(b.x); sv[5] = (short)f2bf(b.y);
    sv[6] = (short)f2bf(b.z); sv[7] = (short)f2bf(b.w);
    *(short8*)&Xbuf[row * 512 + ((slot ^ (row & 7)) * 8)] = sv;
  }
}

// compute one K-half: acc[4][4] += X[64 rows][512] x W-half.
// wf[4] loaded per kc from L2-resident frag-major weights; xf per-i ds_read.
template <bool SWAP>
DEVI void compute_half(const unsigned short* __restrict__ wF,
                       const unsigned short* Xb, int kh, int njb, int lane,
                       f32x4 (&acc)[4][4]) {
  const int l15 = lane & 15, l4 = lane >> 4;
  const short8* wp = (const short8*)wF;
#pragma unroll
  for (int kc = 0; kc < 16; ++kc) {
    short8 wf[4];
#pragma unroll
    for (int j = 0; j < 4; ++j)
      wf[j] = wp[(size_t)((njb + j) * 32 + kh * 16 + kc) * 64 + lane];
#pragma unroll
    for (int i = 0; i < 4; ++i) {
      int row = i * 16 + l15;
      short8 xf = *(const short8*)&Xb[row * 512 + (((kc * 4 + l4) ^ (row & 7)) * 8)];
#pragma unroll
      for (int j = 0; j < 4; ++j)
        acc[i][j] = SWAP
            ? __builtin_amdgcn_mfma_f32_16x16x32_bf16(xf, wf[j], acc[i][j], 0, 0, 0)
            : __builtin_amdgcn_mfma_f32_16x16x32_bf16(wf[j], xf, acc[i][j], 0, 0, 0);
    }
  }
}

DEVI void acc_reset(f32x4 (&acc)[4][4]) {
  const f32x4 zf = {0.f, 0.f, 0.f, 0.f};
#pragma unroll
  for (int i = 0; i < 4; ++i)
#pragma unroll
    for (int j = 0; j < 4; ++j) acc[i][j] = zf;
}

DEVI void epi_qk(const f32x4 (&acc)[4][4], const float* __restrict__ bias,
                 unsigned short* __restrict__ o, float scale, int njb,
                 int b, int t0loc, int l15, int l4) {
#pragma unroll
  for (int j = 0; j < 4; ++j) {
    int ng = njb + j;
    int h = ng >> 2, d0 = (ng & 3) * 16 + l4 * 4;
    float4 bv4 = *(const float4*)&bias[ng * 16 + l4 * 4];
#pragma unroll
    for (int i = 0; i < 4; ++i) {
      int t = t0loc + i * 16 + l15;
      ushort4 pk;
      pk.x = f2bf((acc[i][j][0] + bv4.x) * scale);
      pk.y = f2bf((acc[i][j][1] + bv4.y) * scale);
      pk.z = f2bf((acc[i][j][2] + bv4.z) * scale);
      pk.w = f2bf((acc[i][j][3] + bv4.w) * scale);
      *(ushort4*)&o[((size_t)((b * Hn + h) * Tn + t)) * Dn + d0] = pk;
    }
  }
}

DEVI void epi_v(const f32x4 (&acc)[4][4], const float* __restrict__ bias,
                unsigned short* __restrict__ ov, int njb,
                int b, int t0loc, int l15, int l4) {
#pragma unroll
  for (int j = 0; j < 4; ++j) {
    int n = (njb + j) * 16 + l15;
    int h = n >> 6, d = n & 63;
    float bvl = bias[n];
#pragma unroll
    for (int i = 0; i < 4; ++i) {
      int t0 = t0loc + i * 16 + l4 * 4;
      ushort4 pk;
      pk.x = f2bf(acc[i][j][0] + bvl);
      pk.y = f2bf(acc[i][j][1] + bvl);
      pk.z = f2bf(acc[i][j][2] + bvl);
      pk.w = f2bf(acc[i][j][3] + bvl);
      *(ushort4*)&ov[((size_t)((b * Hn + h) * Dn + d)) * Tn + t0] = pk;
    }
  }
}

// 256 blocks x 1024 thr (1/CU). Waves 0-7 compute, 8-15 stage (separate
// vmcnt FIFOs -> staging never stalls the weight stream). Six phases
// (3 tensors x 2 K-halves), X[2] double buffer, one barrier per phase.
// z=0: Q -> [B][H][T][D]*QSCALE; z=1: K -> [B][H][T][D]; z=2: V -> [B][H][D][T]
__global__ __launch_bounds__(1024) void proj_qkv(
    const float* __restrict__ xqf, const float* __restrict__ xkf,
    const float* __restrict__ xvf, const unsigned short* __restrict__ wFq,
    const unsigned short* __restrict__ wFk, const unsigned short* __restrict__ wFv,
    const float* __restrict__ bq, const float* __restrict__ bk,
    const float* __restrict__ bv, unsigned short* __restrict__ oq,
    unsigned short* __restrict__ ok, unsigned short* __restrict__ ov) {
  __shared__ unsigned short X[2][64 * 512];  // 128 KB
  const int tid = threadIdx.x, lane = tid & 63, w = tid >> 6;
  const int l15 = lane & 15, l4 = lane >> 4;
  const int bid = blockIdx.x;
  const int m0 = (bid >> 1) * 64;
  const int nh = bid & 1;  // XCD-parity-aligned half-weight -> L2-fit
  const int b = m0 >> 11, t0loc = m0 & 2047;
  const bool is_stage = (w >= 8);
  const int stid = tid - 512;
  const int njb = nh * 32 + (w & 7) * 4;  // 8 compute waves x 4 groups

  // prologue: ALL waves stage (z=0, kh=0) -> X[0]
  stage_half<1024>(xqf, m0, 0, X[0], tid);
  __syncthreads();

  f32x4 acc[4][4];

  // phase 0: compute z0/k0 on X[0]; stage z0/k1 -> X[1]
  if (is_stage) {
    stage_half<512>(xqf, m0, 1, X[1], stid);
  } else {
    acc_reset(acc);
    compute_half<false>(wFq, X[0], 0, njb, lane, acc);
  }
  __syncthreads();
  // phase 1: compute z0/k1 on X[1]; stage z1/k0 -> X[0]; write Q
  if (is_stage) {
    stage_half<512>(xkf, m0, 0, X[0], stid);
  } else {
    compute_half<false>(wFq, X[1], 1, njb, lane, acc);
    epi_qk(acc, bq, oq, QSCALE, njb, b, t0loc, l15, l4);
  }
  __syncthreads();
  // phase 2: compute z1/k0 on X[0]; stage z1/k1 -> X[1]
  if (is_stage) {
    stage_half<512>(xkf, m0, 1, X[1], stid);
  } else {
    acc_reset(acc);
    compute_half<false>(wFk, X[0], 0, njb, lane, acc);
  }
  __syncthreads();
  // phase 3: compute z1/k1 on X[1]; stage z2/k0 -> X[0]; write K
  if (is_stage) {
    stage_half<512>(xvf, m0, 0, X[0], stid);
  } else {
    compute_half<false>(wFk, X[1], 1, njb, lane, acc);
    epi_qk(acc, bk, ok, 1.f, njb, b, t0loc, l15, l4);
  }
  __syncthreads();
  // phase 4: compute z2/k0 on X[0]; stage z2/k1 -> X[1]
  if (is_stage) {
    stage_half<512>(xvf, m0, 1, X[1], stid);
  } else {
    acc_reset(acc);
    compute_half<true>(wFv, X[0], 0, njb, lane, acc);
  }
  __syncthreads();
  // phase 5: compute z2/k1 on X[1]; write V (transposed)
  if (!is_stage) {
    compute_half<true>(wFv, X[1], 1, njb, lane, acc);
    epi_v(acc, bv, ov, njb, b, t0loc, l15, l4);
  }
}

// ---------- barrier-free weight-streaming core (proj_out) ----------
DEVI short8 xfrag(const unsigned short* Xlds, int i, int kc, int l15, int l4) {
  int row = i * 16 + l15;
  return *(const short8*)&Xlds[row * 1024 + (((kc * 4 + l4) ^ (row & 7)) * 8)];
}

template <int IB, int NJ, bool SWAP>
DEVI void proj_core(const unsigned short* __restrict__ wF,
                    const unsigned short* Xlds, int njb, int lane,
                    f32x4 (&acc)[IB][NJ]) {
  const int l15 = lane & 15, l4 = lane >> 4;
  const short8* wp = (const short8*)wF;
  short8 wfA[NJ], wfB[NJ];
#pragma unroll
  for (int j = 0; j < NJ; ++j) wfA[j] = wp[(size_t)((njb + j) * 32) * 64 + lane];
#pragma unroll 1
  for (int kc = 0; kc < 32; kc += 2) {
#pragma unroll
    for (int j = 0; j < NJ; ++j)
      wfB[j] = wp[(size_t)((njb + j) * 32 + kc + 1) * 64 + lane];
    short8 xf[IB];
#pragma unroll
    for (int i = 0; i < IB; ++i) xf[i] = xfrag(Xlds, i, kc, l15, l4);
#pragma unroll
    for (int i = 0; i < IB; ++i)
#pragma unroll
      for (int j = 0; j < NJ; ++j)
        acc[i][j] = SWAP
            ? __builtin_amdgcn_mfma_f32_16x16x32_bf16(xf[i], wfA[j], acc[i][j], 0, 0, 0)
            : __builtin_amdgcn_mfma_f32_16x16x32_bf16(wfA[j], xf[i], acc[i][j], 0, 0, 0);
    if (kc + 2 < 32) {
#pragma unroll
      for (int j = 0; j < NJ; ++j)
        wfA[j] = wp[(size_t)((njb + j) * 32 + kc + 2) * 64 + lane];
    }
#pragma unroll
    for (int i = 0; i < IB; ++i) xf[i] = xfrag(Xlds, i, kc + 1, l15, l4);
#pragma unroll
    for (int i = 0; i < IB; ++i)
#pragma unroll
      for (int j = 0; j < NJ; ++j)
        acc[i][j] = SWAP
            ? __builtin_amdgcn_mfma_f32_16x16x32_bf16(xf[i], wfB[j], acc[i][j], 0, 0, 0)
            : __builtin_amdgcn_mfma_f32_16x16x32_bf16(wfB[j], xf[i], acc[i][j], 0, 0, 0);
  }
}

// stage 32x1024 bf16 strip -> LDS via global_load_lds (512 threads)
DEVI void stage32_bf(const unsigned short* __restrict__ src, int m0,
                     unsigned short* Xlds, int tid) {
#pragma unroll
  for (int it = 0; it < 8; ++it) {
    int s = it * 512 + tid;            // 16B-slot index, 4096 total
    int row = s >> 7, sl = s & 127;
    async16(src + (size_t)(m0 + row) * Cn + ((sl ^ (row & 7)) * 8),
            Xlds + (size_t)(it * 512 + (tid & ~63)) * 8);
  }
}

// ---------- final projection: fp32 out [M][N]; 512 blocks x 512 thr (2/CU) ----------
__global__ __launch_bounds__(512, 4) void proj_out(
    const unsigned short* __restrict__ A, const unsigned short* __restrict__ wFo,
    const float* __restrict__ bias, float* __restrict__ o) {
  __shared__ unsigned short Xlds[32 * 1024];
  const int tid = threadIdx.x, lane = tid & 63, w = tid >> 6;
  const int l15 = lane & 15, l4 = lane >> 4;
  const int bid = blockIdx.x;
  const int m0 = (bid >> 1) * 32, nh = bid & 1;

  stage32_bf(A, m0, Xlds, tid);
  __syncthreads();

  const f32x4 zf = {0.f, 0.f, 0.f, 0.f};
  f32x4 acc[2][4];
#pragma unroll
  for (int i = 0; i < 2; ++i)
#pragma unroll
    for (int j = 0; j < 4; ++j) acc[i][j] = zf;

  const int njb = nh * 32 + w * 4;
  proj_core<2, 4, false>(wFo, Xlds, njb, lane, acc);

#pragma unroll
  for (int j = 0; j < 4; ++j) {
    int ng = njb + j;
    float4 bv4 = *(const float4*)&bias[ng * 16 + l4 * 4];
#pragma unroll
    for (int i = 0; i < 2; ++i) {
      int m = m0 + i * 16 + l15;
      float4 ov4;
      ov4.x = acc[i][j][0] + bv4.x;
      ov4.y = acc[i][j][1] + bv4.y;
      ov4.z = acc[i][j][2] + bv4.z;
      ov4.w = acc[i][j][3] + bv4.w;
      *(float4*)&o[(size_t)m * Cn + ng * 16 + l4 * 4] = ov4;
    }
  }
}

// ---------- causal flash attention, 8 waves, swapped QK^T, no-max softmax ----------
__global__ __launch_bounds__(512) void attn_kernel(const unsigned short* __restrict__ qh,
                                                   const unsigned short* __restrict__ kh,
                                                   const unsigned short* __restrict__ vt,
                                                   unsigned short* __restrict__ obf) {
  __shared__ unsigned short Ks[2][64 * 64];   // [key][d], XOR-swizzled, dbuf
  __shared__ unsigned short Vs[2][64 * 64];   // [d][key] (V^T), XOR-swizzled, dbuf
  __shared__ unsigned short Ps[8][16 * 72];   // per-wave P [q=16][72]

  const int tid = threadIdx.x, lane = tid & 63, w = tid >> 6;
  const int l15 = lane & 15, l4 = lane >> 4;
  const int swz = l15 & 7;

  const int bid = blockIdx.x;
  const int j = bid >> 3;
  const int bh = (bid & 7) * 8 + (j & 7);
  const int pair = j >> 3;  // 0..7
  const unsigned short* qb = qh + (size_t)bh * Tn * Dn;
  const unsigned short* kb = kh + (size_t)bh * Tn * Dn;
  const unsigned short* vb = vt + (size_t)bh * Dn * Tn;
  const int b = bh >> 4, h = bh & 15;

  const int srow = lane >> 3, sslot = (lane & 7) ^ (lane >> 3);

  const f32x4 z = {0.f, 0.f, 0.f, 0.f};
  const short ob = (short)0x3F80;  // bf16 1.0
  const short8 ones = {ob, ob, ob, ob, ob, ob, ob, ob};

#pragma unroll 1
  for (int half = 0; half < 2; ++half) {
    const int qt = half == 0 ? pair : 15 - pair;
    const int q0 = qt * 128;
    const int qrow = q0 + w * 16 + l15;

    short8 qf0 = *(const short8*)(qb + (size_t)qrow * Dn + l4 * 8);
    short8 qf1 = *(const short8*)(qb + (size_t)qrow * Dn + 32 + l4 * 8);

    f32x4 o[4];
#pragma unroll
    for (int nd = 0; nd < 4; ++nd) o[nd] = z;
    f32x4 osum = z;  // row-sums via ones-MFMA, layout-aligned with o[nd]

    const int nt = (q0 >> 6) + 2;
    const int ntw = ((q0 + w * 16 + 15) >> 6) + 1;

    {
      const unsigned short* ksrc = kb + (size_t)(w * 8 + srow) * Dn + sslot * 8;
      const unsigned short* vsrc = vb + (size_t)(w * 8 + srow) * Tn + sslot * 8;
      async16(ksrc, &Ks[0][w * 512]);
      async16(vsrc, &Vs[0][w * 512]);
    }

#pragma unroll 1
    for (int t = 0; t < nt; ++t) {
      const int cur = t & 1;
      if (t + 1 < nt) {
        const int kv1 = (t + 1) * 64;
        const unsigned short* ksrc = kb + (size_t)(kv1 + w * 8 + srow) * Dn + sslot * 8;
        const unsigned short* vsrc = vb + (size_t)(w * 8 + srow) * Tn + kv1 + sslot * 8;
        async16(ksrc, &Ks[cur ^ 1][w * 512]);
        async16(vsrc, &Vs[cur ^ 1][w * 512]);
        asm volatile("s_waitcnt vmcnt(2)" ::: "memory");
      } else {
        asm volatile("s_waitcnt vmcnt(0)" ::: "memory");
      }
      __builtin_amdgcn_s_barrier();
      __builtin_amdgcn_sched_barrier(0);

      if (t < ntw) {
        const unsigned short* Kc = &Ks[cur][0];
        const unsigned short* Vc = &Vs[cur][0];

        f32x4 s[4];
#pragma unroll
        for (int ni = 0; ni < 4; ++ni) s[ni] = z;
        __builtin_amdgcn_s_setprio(1);
#pragma unroll
        for (int ni = 0; ni < 4; ++ni) {
          const int rb = (ni * 16 + l15) * 64;
          short8 kf0 = *(const short8*)&Kc[rb + ((l4 ^ swz) * 8)];
          short8 kf1 = *(const short8*)&Kc[rb + (((4 + l4) ^ swz) * 8)];
          s[ni] = __builtin_amdgcn_mfma_f32_16x16x32_bf16(kf0, qf0, s[ni], 0, 0, 0);
          s[ni] = __builtin_amdgcn_mfma_f32_16x16x32_bf16(kf1, qf1, s[ni], 0, 0, 0);
        }
        __builtin_amdgcn_s_setprio(0);

        short8 vf[8];
#pragma unroll
        for (int nd = 0; nd < 4; ++nd) {
          const int rb = (nd * 16 + l15) * 64;
          vf[nd * 2]     = *(const short8*)&Vc[rb + ((l4 ^ swz) * 8)];
          vf[nd * 2 + 1] = *(const short8*)&Vc[rb + (((4 + l4) ^ swz) * 8)];
        }

        const int kq = qrow - t * 64;
        const bool edge = (t * 64 + 63 > q0 + w * 16);
        if (!edge) {
#pragma unroll
          for (int ni = 0; ni < 4; ++ni) {
            ushort4 pk;
#pragma unroll
            for (int r = 0; r < 4; ++r)
              ((unsigned short*)&pk)[r] = f2bf_t(__builtin_amdgcn_exp2f(s[ni][r]));
            *(ushort4*)&Ps[w][l15 * 72 + ni * 16 + l4 * 4] = pk;
          }
        } else {
#pragma unroll
          for (int ni = 0; ni < 4; ++ni) {
            ushort4 pk;
#pragma unroll
            for (int r = 0; r < 4; ++r) {
              float e = __builtin_amdgcn_exp2f(s[ni][r]);
              if ((ni * 16 + l4 * 4 + r) > kq) e = 0.f;
              ((unsigned short*)&pk)[r] = f2bf_t(e);
            }
            *(ushort4*)&Ps[w][l15 * 72 + ni * 16 + l4 * 4] = pk;
          }
        }
        asm volatile("s_waitcnt lgkmcnt(0)" ::: "memory");
        __builtin_amdgcn_sched_barrier(0);

        short8 pf0 = *(const short8*)&Ps[w][l15 * 72 + l4 * 8];
        short8 pf1 = *(const short8*)&Ps[w][l15 * 72 + 32 + l4 * 8];
        __builtin_amdgcn_s_setprio(1);
        osum = __builtin_amdgcn_mfma_f32_16x16x32_bf16(pf0, ones, osum, 0, 0, 0);
        osum = __builtin_amdgcn_mfma_f32_16x16x32_bf16(pf1, ones, osum, 0, 0, 0);
#pragma unroll
        for (int nd = 0; nd < 4; ++nd) {
          o[nd] = __builtin_amdgcn_mfma_f32_16x16x32_bf16(pf0, vf[nd * 2], o[nd], 0, 0, 0);
          o[nd] = __builtin_amdgcn_mfma_f32_16x16x32_bf16(pf1, vf[nd * 2 + 1], o[nd], 0, 0, 0);
        }
        __builtin_amdgcn_s_setprio(0);
      }

      __builtin_amdgcn_sched_barrier(0);
      __builtin_amdgcn_s_barrier();
    }

#pragma unroll
    for (int r = 0; r < 4; ++r) {
      float inv = __builtin_amdgcn_rcpf(osum[r]);
      int tq = q0 + w * 16 + l4 * 4 + r;
      size_t base = ((size_t)(b * Tn + tq)) * Cn + h * 64;
#pragma unroll
      for (int nd = 0; nd < 4; ++nd)
        obf[base + nd * 16 + l15] = f2bf(o[nd][r] * inv);
    }
  }
}

extern "C" void kernel_launch(void* const* d_in, const int* in_sizes, int n_in,
                              void* d_out, int out_size, void* d_ws, size_t ws_size,
                              hipStream_t stream) {
  const float* q   = (const float*)d_in[0];
  const float* k   = (const float*)d_in[1];
  const float* v   = (const float*)d_in[2];
  const float* w_q = (const float*)d_in[3];
  const float* b_q = (const float*)d_in[4];
  const float* w_k = (const float*)d_in[5];
  const float* b_k = (const float*)d_in[6];
  const float* w_v = (const float*)d_in[7];
  const float* b_v = (const float*)d_in[8];
  const float* w_o = (const float*)d_in[9];
  const float* b_o = (const float*)d_in[10];

  char* ws = (char*)d_ws;
  const size_t MB = 1u << 20;
  unsigned short* qhp  = (unsigned short*)(ws);            // 16 MB
  unsigned short* khp  = (unsigned short*)(ws + 16 * MB);  // 16 MB
  unsigned short* vtp  = (unsigned short*)(ws + 32 * MB);  // 16 MB
  unsigned short* aout = (unsigned short*)(ws + 48 * MB);  // 16 MB
  unsigned short* wqT  = (unsigned short*)(ws + 64 * MB);  // 2 MB each
  unsigned short* wkT  = (unsigned short*)(ws + 66 * MB);
  unsigned short* wvT  = (unsigned short*)(ws + 68 * MB);
  unsigned short* woT  = (unsigned short*)(ws + 70 * MB);

  transpose_cvt4<<<dim3(32, 32, 4), dim3(32, 8), 0, stream>>>(
      w_q, w_k, w_v, w_o, wqT, wkT, wvT, woT);

  proj_qkv<<<256, 1024, 0, stream>>>(q, k, v, wqT, wkT, wvT,
                                     b_q, b_k, b_v, qhp, khp, vtp);

  attn_kernel<<<512, 512, 0, stream>>>(qhp, khp, vtp, aout);

  proj_out<<<512, 512, 0, stream>>>(aout, woT, b_o, (float*)d_out);
}